// Round 18
// baseline (78.848 us; speedup 1.0000x reference)
//
#include <hip/hip_runtime.h>
#include <math.h>

namespace {

constexpr int Hh = 384;
constexpr int Ww = 384;
constexpr int Bb = 4;
constexpr int HW = Hh * Ww;          // 147456
constexpr int NPIX = Bb * HW;        // 589824
constexpr int ROUNDS = 10;           // 2 mean-field iterations per round
constexpr int TPB = 256;

// 2D tiling: each block owns a 64x8 tile (2 px/thread), 6x48 tiles/batch
constexpr int TILE_W = 64;
constexpr int TILE_H = 8;
constexpr int TX = Ww / TILE_W;              // 6
constexpr int TY = Hh / TILE_H;              // 48
constexpr int BLKS_PER_B = TX * TY;          // 288
constexpr int NBLK = Bb * BLKS_PER_B;        // 1152

// width-2 halo staged per compute round: rows row0-2..row0+9 (12), cols col0-8..col0+71 (80 B)
constexpr int H2DW = 20;                     // 80 B / 4
constexpr int H2TOT = 12 * H2DW;             // 240 dwords

// intermediate s_{2r+1}: extended region rows row0-1..row0+8 (10) x cols col0-1..col0+64 (66)
constexpr int MIDS = 68;                     // byte stride
constexpr int NRING = 148;                   // ring pixels of the 10x66 region

// prologue LDS: fmS[3][12][70] and wdir[4][11][68]
constexpr int FMR = 12, FMC = 70, FMPL = FMR * FMC;       // 840
constexpr int FMTOT = 3 * FMPL;                           // 2520
constexpr int QR = 11, QC = 68, QPL = QR * QC;            // 748
constexpr int QTOT = 4 * QPL;                             // 2992

__device__ __forceinline__ float fsub_rn_(float a, float b) {
    return __fadd_rn(a, -b);
}

__device__ __forceinline__ unsigned ld_agent_u32(const void* p) {
    return __hip_atomic_load((const unsigned*)p, __ATOMIC_RELAXED,
                             __HIP_MEMORY_SCOPE_AGENT);
}
__device__ __forceinline__ void st_agent_u16(void* p, unsigned short v) {
    __hip_atomic_store((unsigned short*)p, v, __ATOMIC_RELAXED,
                       __HIP_MEMORY_SCOPE_AGENT);
}
__device__ __forceinline__ int ld_agent_i32(const int* p) {
    return __hip_atomic_load(p, __ATOMIC_RELAXED, __HIP_MEMORY_SCOPE_AGENT);
}
__device__ __forceinline__ void st_agent_i32(int* p, int v) {
    __hip_atomic_store(p, v, __ATOMIC_RELAXED, __HIP_MEMORY_SCOPE_AGENT);
}

// one mean-field pixel update; base -> top-left tap. FP order identical to ref.
// (R15 version verbatim -- proven 52.4us / absmax 0.0 / no spill.)
template <int STRIDE>
__device__ __forceinline__ unsigned mf_state(const unsigned char* base,
                                             const float* w9, float tpx,
                                             float Lg45, float Lg55) {
    float a0 = 0.0f, a1 = 0.0f;
#pragma unroll
    for (int ki = 0; ki < 3; ++ki) {
#pragma unroll
        for (int kj = 0; kj < 3; ++kj) {
            const int k = ki * 3 + kj;
            unsigned char s = base[ki * STRIDE + kj];   // garbage when w9[k]==0 -> +0.0
            float u0 = (s & 1) ? Lg55 : Lg45;
            float u1 = (s & 2) ? Lg55 : Lg45;
            a0 = __fadd_rn(a0, __fmul_rn(u0, w9[k]));
            a1 = __fadd_rn(a1, __fmul_rn(u1, w9[k]));
        }
    }
    float f0 = expf(-a0);
    float f1 = __fmul_rn(expf(-a1), tpx);
    f0 = __fadd_rn(f0, 1e-6f);
    f1 = __fadd_rn(f1, 1e-6f);
    float S = __fadd_rn(f0, f1);
    float f0n = __fdiv_rn(f0, S);
    float f1n = __fdiv_rn(f1, S);
    return (f0n > 0.5f ? 1u : 0u) | (f1n > 0.5f ? 2u : 0u);
}

__device__ __forceinline__ void ring_coords(int ri, int& er, int& ec) {
    if (ri < 66)       { er = 0;        ec = ri; }
    else if (ri < 132) { er = 9;        ec = ri - 66; }
    else if (ri < 140) { er = ri - 131; ec = 0; }     // 1..8
    else               { er = ri - 139; ec = 65; }    // 1..8
}

// Flags/skip protocol identical to R14/R15 (proven). New: conv[r] striped
// counters — a block that SKIPS round r increments conv[r]; when a block at
// round r>=2 sees conv[r-1]==NBLK, every block skipped r-1 => field globally
// stable => my LDS region is current => output = staged bytes; publish
// ((ROUNDS+2)<<2) (part always satisfies any poll; changed bits 0 so
// stragglers skip too) and break to the epilogue. Bit-exact by induction.
__global__ __launch_bounds__(TPB, 6) void fused_kernel(
        const float* __restrict__ x, const float* __restrict__ t,
        const float* __restrict__ fm, float* __restrict__ out,
        int* __restrict__ arrive, int* __restrict__ flags,
        int* __restrict__ conv, int* __restrict__ partial,
        unsigned char* __restrict__ st0, unsigned char* __restrict__ st1) {
    const int tid = threadIdx.x;
    const int bid = blockIdx.x;
    const int b = bid / BLKS_PER_B;
    const int rr_ = bid - b * BLKS_PER_B;
    const int ty = rr_ / TX, tx = rr_ - ty * TX;
    const int row0 = ty * TILE_H, col0 = tx * TILE_W;
    const int tr = tid >> 5;              // 0..7
    const int tc = (tid & 31) * 2;        // 0..62
    const int row = row0 + tr, col = col0 + tc;
    const int hw = row * Ww + col;
    const int gp = b * HW + hw;           // gp % 2 == 0

    // lanes 0..7 of wave 0 poll one neighbor each
    bool nactive = false;
    const int* nflag = nullptr;
    if (tid < 8) {
        const int l2 = (tid < 4) ? tid : tid + 1;       // skip center
        const int dy = l2 / 3 - 1, dx = l2 - (l2 / 3) * 3 - 1;
        const int nty = ty + dy, ntx = tx + dx;
        if (nty >= 0 && nty < TY && ntx >= 0 && ntx < TX) {
            nactive = true;
            nflag = &flags[(b * BLKS_PER_B + nty * TX + ntx) << 4];
        }
    }

    const float Lg45 = (float)(-log((double)0.45f));
    const float Lg55 = (float)(-log((double)0.55f));

    // ---- FIRST: s_0 init + flag publish (prologue off the chain) ----
    float2 xv = reinterpret_cast<const float2*>(x)[gp >> 1];
    float2 tv = reinterpret_cast<const float2*>(t)[gp >> 1];
    const float tj[2] = {tv.x, tv.y};
    {
        unsigned short pack =
            (unsigned short)(((__fmul_rn(xv.x, tv.x) > 0.5f) ? 2u : 1u) |
                             (((__fmul_rn(xv.y, tv.y) > 0.5f) ? 2u : 1u) << 8));
        st_agent_u16(st0 + gp, pack);
    }
    __syncthreads();                      // drain s_0 stores (vmcnt 0)
    if (tid == 0) st_agent_i32(&flags[bid << 4], (1 << 2) | 3);

    // ---- prologue: shared-memory weight factory (R15, proven exact) ----
    __shared__ float pbuf[FMTOT + QTOT];  // fmS | wdir
    float* fmS = pbuf;
    float* wdir = pbuf + FMTOT;
    const float* fmb = fm + (size_t)b * 3 * HW;
    for (int i = tid; i < FMTOT; i += TPB) {
        const int c = i / FMPL, rem = i - c * FMPL;
        const int r = rem / FMC, fc = rem - r * FMC;
        const int ir = min(max(row0 - 2 + r, 0), Hh - 1);
        const int ic = min(max(col0 - 3 + fc, 0), Ww - 1);
        fmS[i] = fmb[c * HW + ir * Ww + ic];
    }
    __syncthreads();

    const float SPK1 = __fdiv_rn(1.0f, 1800.0f);
    const float SPK2 = __fdiv_rn(2.0f, 1800.0f);
    auto wtap = [&](int fr, int fc, float c0, float c1, float c2, float spk) {
        float d0 = fsub_rn_(__fadd_rn(fmS[0 * FMPL + fr * FMC + fc], 10.0f), c0);
        float d1 = fsub_rn_(__fadd_rn(fmS[1 * FMPL + fr * FMC + fc], 10.0f), c1);
        float d2 = fsub_rn_(__fadd_rn(fmS[2 * FMPL + fr * FMC + fc], 10.0f), c2);
        float ss = __fadd_rn(__fadd_rn(__fmul_rn(d0, d0), __fmul_rn(d1, d1)),
                             __fmul_rn(d2, d2));
        float color = __fmul_rn(-ss, 2.0f);   // == __fdiv_rn(-ss,0.5f) exactly
        return __fmul_rn(3.0f, expf(fsub_rn_(color, spk)));
    };
    for (int i = tid; i < QPL; i += TPB) {
        const int qr = i / QC, qcc = i - qr * QC;
        const int ir = row0 - 1 + qr, ic = col0 - 2 + qcc;
        float w0 = 0.0f, w1 = 0.0f, w2 = 0.0f, w3 = 0.0f;
        if (ir >= 0 && ir < Hh && ic >= 0 && ic < Ww) {
            const int fr = qr + 1, fc = qcc + 1;
            float c0 = __fadd_rn(fmS[0 * FMPL + fr * FMC + fc], 10.0f);
            float c1 = __fadd_rn(fmS[1 * FMPL + fr * FMC + fc], 10.0f);
            float c2 = __fadd_rn(fmS[2 * FMPL + fr * FMC + fc], 10.0f);
            const bool up = (ir - 1 >= 0), lf = (ic - 1 >= 0), rg = (ic + 1 < Ww);
            if (up && lf) w0 = wtap(fr - 1, fc - 1, c0, c1, c2, SPK2);
            if (up)       w1 = wtap(fr - 1, fc,     c0, c1, c2, SPK1);
            if (up && rg) w2 = wtap(fr - 1, fc + 1, c0, c1, c2, SPK2);
            if (lf)       w3 = wtap(fr,     fc - 1, c0, c1, c2, SPK1);
        }
        wdir[0 * QPL + i] = w0;
        wdir[1 * QPL + i] = w1;
        wdir[2 * QPL + i] = w2;
        wdir[3 * QPL + i] = w3;
    }
    __syncthreads();

    // assemble own 2 px weights (register state identical to R15)
    float wall[2][9];
#pragma unroll
    for (int j = 0; j < 2; ++j) {
        const int qp = (tr + 1) * QC + (tc + j + 2);
        wall[j][0] = wdir[0 * QPL + qp];
        wall[j][1] = wdir[1 * QPL + qp];
        wall[j][2] = wdir[2 * QPL + qp];
        wall[j][3] = wdir[3 * QPL + qp];
        wall[j][4] = 3.0f;
        wall[j][5] = wdir[3 * QPL + qp + 1];        // E = right's W
        wall[j][6] = wdir[2 * QPL + qp + QC - 1];   // SW = down-left's NE
        wall[j][7] = wdir[1 * QPL + qp + QC];       // S = down's N
        wall[j][8] = wdir[0 * QPL + qp + QC + 1];   // SE = down-right's NW
    }
    // ring weights
    bool ringv = false;
    int rer = 0, rec = 0;
    float rw[9] = {0, 0, 0, 0, 0, 0, 0, 0, 0};
    float rt = 0.0f;
    if (tid < NRING) {
        ring_coords(tid, rer, rec);
        const int irow = row0 - 1 + rer, icol = col0 - 1 + rec;
        ringv = (irow >= 0 && irow < Hh && icol >= 0 && icol < Ww);
        if (ringv) {
            const int qp = rer * QC + (rec + 1);
            rw[0] = wdir[0 * QPL + qp];
            rw[1] = wdir[1 * QPL + qp];
            rw[2] = wdir[2 * QPL + qp];
            rw[3] = wdir[3 * QPL + qp];
            rw[4] = 3.0f;
            rw[5] = wdir[3 * QPL + qp + 1];
            rw[6] = wdir[2 * QPL + qp + QC - 1];
            rw[7] = wdir[1 * QPL + qp + QC];
            rw[8] = wdir[0 * QPL + qp + QC + 1];
            rt = t[(size_t)b * HW + irow * Ww + icol];
        }
    }

    __shared__ unsigned lds_h2[H2TOT];            // staged region (single buffer)
    __shared__ unsigned char lds_mid[10 * MIDS];  // s_{2r+1}, 10x66 used
    __shared__ int sskip;
    __shared__ int sdone;
    __shared__ int schg[4];
    __shared__ int sred[4];

    int pchg = 1;                          // changed_{r-1}, block-uniform
    float o0 = 0.0f, o1 = 0.0f;

    // ---- 10 rounds x 2 iterations (R15 structure + gdone short-circuit) ----
    for (int r = 0; r < ROUNDS; ++r) {
        const bool fin = (r == ROUNDS - 1);
        const unsigned char* cur = (r & 1) ? st1 : st0;
        unsigned char* nxt = (r & 1) ? st0 : st1;

        // gdone: conv[r-1]==NBLK => all blocks skipped r-1 => stable field
        if (r >= 2) {
            int v = 0;
            if (tid < 16) v = ld_agent_i32(&conv[((r - 1) * 16 + tid) << 4]);
            if (tid < 64) {
#pragma unroll
                for (int off = 1; off < 64; off <<= 1) v += __shfl_xor(v, off, 64);
                if (tid == 0) sdone = (v >= NBLK);
            }
            __syncthreads();
            if (sdone != 0) {
                if (tid == 0)
                    st_agent_i32(&flags[bid << 4], (ROUNDS + 2) << 2);
                const unsigned char* h2b = (const unsigned char*)lds_h2;
                o0 = (h2b[(tr + 2) * 80 + tc + 8] & 2) ? 1.0f : 0.0f;
                o1 = (h2b[(tr + 2) * 80 + tc + 9] & 2) ? 1.0f : 0.0f;
                break;
            }
        }

        // poll: all neighbors part >= r+1; capture their changed_{r-1}
        if (tid < 64) {
            int nchg = 0;
            for (;;) {
                bool ok = true;
                if (nactive) {
                    int f = ld_agent_i32(nflag);
                    int part = f >> 2;
                    ok = (part >= r + 1);
                    if (ok) nchg = (part == r + 1) ? ((f >> 1) & 1) : (f & 1);
                }
                if (__all(ok)) break;
                __builtin_amdgcn_s_sleep(1);
            }
            bool unch = nactive ? (nchg == 0) : true;
            int au = __all(unch);
            if (tid == 0) sskip = au;
        }
        __syncthreads();
        const bool skip = (r > 0) && (sskip != 0) && (pchg == 0);

        const unsigned char* h2b = (const unsigned char*)lds_h2;
        unsigned n2[2];
        int chg;

        if (skip) {
            n2[0] = h2b[(tr + 2) * 80 + tc + 8];
            n2[1] = h2b[(tr + 2) * 80 + tc + 9];
            chg = 0;
            if (tid == 0) {
                if (!fin)
                    st_agent_i32(&flags[bid << 4],
                                 ((r + 2) << 2) | (0 << 1) | pchg);
                __hip_atomic_fetch_add(&conv[(r * 16 + (bid & 15)) << 4], 1,
                                       __ATOMIC_RELAXED, __HIP_MEMORY_SCOPE_AGENT);
            }
        } else {
            if (tid < H2TOT) {
                const unsigned char* base2 =
                    cur + (size_t)b * HW + (row0 - 2) * Ww + (col0 - 8);
                const int hr = tid / H2DW, hc = tid - hr * H2DW;
                lds_h2[tid] = ld_agent_u32(base2 + hr * Ww + hc * 4);
            }
            __syncthreads();

#pragma unroll
            for (int j = 0; j < 2; ++j) {
                unsigned m = mf_state<80>(h2b + (tr + 1) * 80 + tc + 7 + j,
                                          wall[j], tj[j], Lg45, Lg55);
                lds_mid[(tr + 1) * MIDS + tc + j + 1] = (unsigned char)m;
            }
            if (ringv) {
                unsigned m = mf_state<80>(h2b + rer * 80 + rec + 6,
                                          rw, rt, Lg45, Lg55);
                lds_mid[rer * MIDS + rec] = (unsigned char)m;
            }
            __syncthreads();

#pragma unroll
            for (int j = 0; j < 2; ++j)
                n2[j] = mf_state<MIDS>(lds_mid + tr * MIDS + tc + j,
                                       wall[j], tj[j], Lg45, Lg55);

            bool diff = (n2[0] != (unsigned)h2b[(tr + 2) * 80 + tc + 8]) ||
                        (n2[1] != (unsigned)h2b[(tr + 2) * 80 + tc + 9]);
            {
                int any = __any(diff);
                if ((tid & 63) == 0) schg[tid >> 6] = any;
            }
            if (!fin)
                st_agent_u16(nxt + gp, (unsigned short)(n2[0] | (n2[1] << 8)));
            __syncthreads();              // drains state stores + schg writes
            chg = (schg[0] | schg[1] | schg[2] | schg[3]) ? 1 : 0;
            if (!fin && tid == 0)
                st_agent_i32(&flags[bid << 4], ((r + 2) << 2) | (chg << 1) | pchg);
        }
        pchg = chg;

        if (fin) {
            o0 = (n2[0] & 2) ? 1.0f : 0.0f;
            o1 = (n2[1] & 2) ? 1.0f : 0.0f;
        }
    }

    // ---- epilogue: output + final global sync + valid ----
    reinterpret_cast<float2*>(out)[gp >> 1] = make_float2(o0, o1);
    {
        int cnt = (o0 != 0.0f) + (o1 != 0.0f);
        const int lane = tid & 63;
        const int wv = tid >> 6;
#pragma unroll
        for (int off = 32; off; off >>= 1) cnt += __shfl_down(cnt, off, 64);
        if (lane == 0) sred[wv] = cnt;
    }
    __syncthreads();
    if (tid == 0) {
        int tot = sred[0] + sred[1] + sred[2] + sred[3];
        st_agent_i32(&partial[bid], tot);
    }
    __syncthreads();                      // drain partial store
    if (tid == 0)
        __hip_atomic_fetch_add(&arrive[(bid & 15) << 4], 1,
                               __ATOMIC_RELAXED, __HIP_MEMORY_SCOPE_AGENT);
    if (bid == 0) {
        if (tid < 64) {
            for (;;) {
                int v = 0;
                if (tid < 16) v = ld_agent_i32(&arrive[tid << 4]);
#pragma unroll
                for (int off = 1; off < 64; off <<= 1) v += __shfl_xor(v, off, 64);
                if (v >= NBLK) break;
                __builtin_amdgcn_s_sleep(1);
            }
        }
        __syncthreads();
        const int wv = tid >> 6;          // batch 0..3
        const int lane = tid & 63;
        const int base = wv * BLKS_PER_B; // 288 partials per batch = 4x64 + 32
        int s = 0;
#pragma unroll
        for (int k = 0; k < 4; ++k) s += ld_agent_i32(&partial[base + 64 * k + lane]);
        if (lane < 32) s += ld_agent_i32(&partial[base + 256 + lane]);
#pragma unroll
        for (int off = 32; off; off >>= 1) s += __shfl_down(s, off, 64);
        if (lane == 0) {
            float cf = (float)s;
            const float lo = (float)(147456.0 * 0.05);
            const float hi = (float)(147456.0 * 0.95);
            out[NPIX + wv] = (cf >= lo && cf <= hi) ? 1.0f : 0.0f;
        }
    }
}

}  // namespace

extern "C" void kernel_launch(void* const* d_in, const int* in_sizes, int n_in,
                              void* d_out, int out_size, void* d_ws, size_t ws_size,
                              hipStream_t stream) {
    const float* x  = (const float*)d_in[0];
    const float* tg = (const float*)d_in[1];
    const float* fm = (const float*)d_in[2];
    float* out = (float*)d_out;

    char* ws = (char*)d_ws;
    // layout (bytes):
    //   arrive : 0      .. 1024      (16 x 64B)
    //   flags  : 1024   .. 74752     (1152 x 64B)
    //   conv   : 74752  .. 84992     (10 rounds x 16 stripes x 64B)
    //   partial: 84992  .. 89600
    //   pad    : 89600  .. 92160     (static during rounds -> overhang-safe)
    //   st0    : 92160  .. +NPIX
    //   pad    : 2048
    //   st1    : .. +NPIX
    int* arrive  = (int*)ws;
    int* flags   = (int*)(ws + 1024);
    int* conv    = (int*)(ws + 74752);
    int* partial = (int*)(ws + 84992);
    unsigned char* st0 = (unsigned char*)(ws + 92160);
    unsigned char* st1 = st0 + NPIX + 2048;

    // zero arrive + flags + conv every call (graph-captured)
    (void)hipMemsetAsync(ws, 0, 84992, stream);

    fused_kernel<<<NBLK, TPB, 0, stream>>>(x, tg, fm, out, arrive, flags,
                                           conv, partial, st0, st1);
}

// Round 19
// 52.211 us; speedup vs baseline: 1.5102x; 1.5102x over previous
//
#include <hip/hip_runtime.h>
#include <math.h>

namespace {

constexpr int Hh = 384;
constexpr int Ww = 384;
constexpr int Bb = 4;
constexpr int HW = Hh * Ww;          // 147456
constexpr int NPIX = Bb * HW;        // 589824
constexpr int ROUNDS = 10;           // 2 mean-field iterations per round
constexpr int TPB = 256;

// 2D tiling: each block owns a 64x8 tile (2 px/thread), 6x48 tiles/batch
constexpr int TILE_W = 64;
constexpr int TILE_H = 8;
constexpr int TX = Ww / TILE_W;              // 6
constexpr int TY = Hh / TILE_H;              // 48
constexpr int BLKS_PER_B = TX * TY;          // 288
constexpr int NBLK = Bb * BLKS_PER_B;        // 1152

// width-2 halo staged per compute round: rows row0-2..row0+9 (12), cols col0-8..col0+71 (80 B)
constexpr int H2DW = 20;                     // 80 B / 4
constexpr int H2TOT = 12 * H2DW;             // 240 dwords

// intermediate s_{2r+1}: extended region rows row0-1..row0+8 (10) x cols col0-1..col0+64 (66)
constexpr int MIDS = 68;                     // byte stride
constexpr int NRING = 148;                   // ring pixels of the 10x66 region

// prologue LDS: fmS[3][12][70] and wdir[4][11][68]
constexpr int FMR = 12, FMC = 70, FMPL = FMR * FMC;       // 840
constexpr int FMTOT = 3 * FMPL;                           // 2520
constexpr int QR = 11, QC = 68, QPL = QR * QC;            // 748
constexpr int QTOT = 4 * QPL;                             // 2992

__device__ __forceinline__ float fsub_rn_(float a, float b) {
    return __fadd_rn(a, -b);
}

__device__ __forceinline__ unsigned ld_agent_u32(const void* p) {
    return __hip_atomic_load((const unsigned*)p, __ATOMIC_RELAXED,
                             __HIP_MEMORY_SCOPE_AGENT);
}
__device__ __forceinline__ void st_agent_u16(void* p, unsigned short v) {
    __hip_atomic_store((unsigned short*)p, v, __ATOMIC_RELAXED,
                       __HIP_MEMORY_SCOPE_AGENT);
}
__device__ __forceinline__ int ld_agent_i32(const int* p) {
    return __hip_atomic_load(p, __ATOMIC_RELAXED, __HIP_MEMORY_SCOPE_AGENT);
}
__device__ __forceinline__ void st_agent_i32(int* p, int v) {
    __hip_atomic_store(p, v, __ATOMIC_RELAXED, __HIP_MEMORY_SCOPE_AGENT);
}

// one mean-field pixel update; base -> top-left tap. FP order identical to ref.
template <int STRIDE>
__device__ __forceinline__ unsigned mf_state(const unsigned char* base,
                                             const float* w9, float tpx,
                                             float Lg45, float Lg55) {
    float a0 = 0.0f, a1 = 0.0f;
#pragma unroll
    for (int ki = 0; ki < 3; ++ki) {
#pragma unroll
        for (int kj = 0; kj < 3; ++kj) {
            const int k = ki * 3 + kj;
            unsigned char s = base[ki * STRIDE + kj];   // garbage when w9[k]==0 -> +0.0
            float u0 = (s & 1) ? Lg55 : Lg45;
            float u1 = (s & 2) ? Lg55 : Lg45;
            a0 = __fadd_rn(a0, __fmul_rn(u0, w9[k]));
            a1 = __fadd_rn(a1, __fmul_rn(u1, w9[k]));
        }
    }
    float f0 = expf(-a0);
    float f1 = __fmul_rn(expf(-a1), tpx);
    f0 = __fadd_rn(f0, 1e-6f);
    f1 = __fadd_rn(f1, 1e-6f);
    float S = __fadd_rn(f0, f1);
    float f0n = __fdiv_rn(f0, S);
    float f1n = __fdiv_rn(f1, S);
    return (f0n > 0.5f ? 1u : 0u) | (f1n > 0.5f ? 2u : 0u);
}

__device__ __forceinline__ void ring_coords(int ri, int& er, int& ec) {
    if (ri < 66)       { er = 0;        ec = ri; }
    else if (ri < 132) { er = 9;        ec = ri - 66; }
    else if (ri < 140) { er = ri - 131; ec = 0; }     // 1..8
    else               { er = ri - 139; ec = 65; }    // 1..8
}

// Flags/skip protocol identical to R14 (proven): word = ((q+2)<<2) |
// (changed_q<<1) | changed_{q-1}; round r waits parts >= r+1; skip iff all 9
// changed_{r-1}==0 (then LDS region is current, nothing staged/stored).
__global__ __launch_bounds__(TPB, 6) void fused_kernel(
        const float* __restrict__ x, const float* __restrict__ t,
        const float* __restrict__ fm, float* __restrict__ out,
        int* __restrict__ arrive, int* __restrict__ flags,
        int* __restrict__ partial,
        unsigned char* __restrict__ st0, unsigned char* __restrict__ st1) {
    const int tid = threadIdx.x;
    const int bid = blockIdx.x;
    const int b = bid / BLKS_PER_B;
    const int rr_ = bid - b * BLKS_PER_B;
    const int ty = rr_ / TX, tx = rr_ - ty * TX;
    const int row0 = ty * TILE_H, col0 = tx * TILE_W;
    const int tr = tid >> 5;              // 0..7
    const int tc = (tid & 31) * 2;        // 0..62
    const int row = row0 + tr, col = col0 + tc;
    const int hw = row * Ww + col;
    const int gp = b * HW + hw;           // gp % 2 == 0

    // lanes 0..7 of wave 0 poll one neighbor each
    bool nactive = false;
    const int* nflag = nullptr;
    if (tid < 8) {
        const int l2 = (tid < 4) ? tid : tid + 1;       // skip center
        const int dy = l2 / 3 - 1, dx = l2 - (l2 / 3) * 3 - 1;
        const int nty = ty + dy, ntx = tx + dx;
        if (nty >= 0 && nty < TY && ntx >= 0 && ntx < TX) {
            nactive = true;
            nflag = &flags[(b * BLKS_PER_B + nty * TX + ntx) << 4];
        }
    }

    const float Lg45 = (float)(-log((double)0.45f));
    const float Lg55 = (float)(-log((double)0.55f));

    // ---- FIRST: s_0 init + flag publish (takes prologue off the chain) ----
    float2 xv = reinterpret_cast<const float2*>(x)[gp >> 1];
    float2 tv = reinterpret_cast<const float2*>(t)[gp >> 1];
    const float tj[2] = {tv.x, tv.y};
    {
        unsigned short pack =
            (unsigned short)(((__fmul_rn(xv.x, tv.x) > 0.5f) ? 2u : 1u) |
                             (((__fmul_rn(xv.y, tv.y) > 0.5f) ? 2u : 1u) << 8));
        st_agent_u16(st0 + gp, pack);
    }
    __syncthreads();                      // drain s_0 stores (vmcnt 0)
    if (tid == 0) st_agent_i32(&flags[bid << 4], (1 << 2) | 3);

    // ---- prologue: shared-memory weight factory ----
    __shared__ float pbuf[FMTOT + QTOT];  // fmS | wdir
    float* fmS = pbuf;
    float* wdir = pbuf + FMTOT;
    const float* fmb = fm + (size_t)b * 3 * HW;
    for (int i = tid; i < FMTOT; i += TPB) {
        const int c = i / FMPL, rem = i - c * FMPL;
        const int r = rem / FMC, fc = rem - r * FMC;
        const int ir = min(max(row0 - 2 + r, 0), Hh - 1);
        const int ic = min(max(col0 - 3 + fc, 0), Ww - 1);
        fmS[i] = fmb[c * HW + ir * Ww + ic];
    }
    __syncthreads();

    const float SPK1 = __fdiv_rn(1.0f, 1800.0f);
    const float SPK2 = __fdiv_rn(2.0f, 1800.0f);
    auto wtap = [&](int fr, int fc, float c0, float c1, float c2, float spk) {
        float d0 = fsub_rn_(__fadd_rn(fmS[0 * FMPL + fr * FMC + fc], 10.0f), c0);
        float d1 = fsub_rn_(__fadd_rn(fmS[1 * FMPL + fr * FMC + fc], 10.0f), c1);
        float d2 = fsub_rn_(__fadd_rn(fmS[2 * FMPL + fr * FMC + fc], 10.0f), c2);
        float ss = __fadd_rn(__fadd_rn(__fmul_rn(d0, d0), __fmul_rn(d1, d1)),
                             __fmul_rn(d2, d2));
        float color = __fmul_rn(-ss, 2.0f);   // == __fdiv_rn(-ss,0.5f) exactly
        return __fmul_rn(3.0f, expf(fsub_rn_(color, spk)));
    };
    for (int i = tid; i < QPL; i += TPB) {
        const int qr = i / QC, qcc = i - qr * QC;
        const int ir = row0 - 1 + qr, ic = col0 - 2 + qcc;
        float w0 = 0.0f, w1 = 0.0f, w2 = 0.0f, w3 = 0.0f;
        if (ir >= 0 && ir < Hh && ic >= 0 && ic < Ww) {
            const int fr = qr + 1, fc = qcc + 1;
            float c0 = __fadd_rn(fmS[0 * FMPL + fr * FMC + fc], 10.0f);
            float c1 = __fadd_rn(fmS[1 * FMPL + fr * FMC + fc], 10.0f);
            float c2 = __fadd_rn(fmS[2 * FMPL + fr * FMC + fc], 10.0f);
            const bool up = (ir - 1 >= 0), lf = (ic - 1 >= 0), rg = (ic + 1 < Ww);
            if (up && lf) w0 = wtap(fr - 1, fc - 1, c0, c1, c2, SPK2);
            if (up)       w1 = wtap(fr - 1, fc,     c0, c1, c2, SPK1);
            if (up && rg) w2 = wtap(fr - 1, fc + 1, c0, c1, c2, SPK2);
            if (lf)       w3 = wtap(fr,     fc - 1, c0, c1, c2, SPK1);
        }
        wdir[0 * QPL + i] = w0;
        wdir[1 * QPL + i] = w1;
        wdir[2 * QPL + i] = w2;
        wdir[3 * QPL + i] = w3;
    }
    __syncthreads();

    // assemble own 2 px weights (lattice qr=tr+1, qcc=tc+j+2)
    float wall[2][9];
#pragma unroll
    for (int j = 0; j < 2; ++j) {
        const int qp = (tr + 1) * QC + (tc + j + 2);
        wall[j][0] = wdir[0 * QPL + qp];
        wall[j][1] = wdir[1 * QPL + qp];
        wall[j][2] = wdir[2 * QPL + qp];
        wall[j][3] = wdir[3 * QPL + qp];
        wall[j][4] = 3.0f;
        wall[j][5] = wdir[3 * QPL + qp + 1];        // E = right's W
        wall[j][6] = wdir[2 * QPL + qp + QC - 1];   // SW = down-left's NE
        wall[j][7] = wdir[1 * QPL + qp + QC];       // S = down's N
        wall[j][8] = wdir[0 * QPL + qp + QC + 1];   // SE = down-right's NW
    }
    // ring weights (lattice qr=er, qcc=ec+1)
    bool ringv = false;
    int rer = 0, rec = 0;
    float rw[9] = {0, 0, 0, 0, 0, 0, 0, 0, 0};
    float rt = 0.0f;
    if (tid < NRING) {
        ring_coords(tid, rer, rec);
        const int irow = row0 - 1 + rer, icol = col0 - 1 + rec;
        ringv = (irow >= 0 && irow < Hh && icol >= 0 && icol < Ww);
        if (ringv) {
            const int qp = rer * QC + (rec + 1);
            rw[0] = wdir[0 * QPL + qp];
            rw[1] = wdir[1 * QPL + qp];
            rw[2] = wdir[2 * QPL + qp];
            rw[3] = wdir[3 * QPL + qp];
            rw[4] = 3.0f;
            rw[5] = wdir[3 * QPL + qp + 1];
            rw[6] = wdir[2 * QPL + qp + QC - 1];
            rw[7] = wdir[1 * QPL + qp + QC];
            rw[8] = wdir[0 * QPL + qp + QC + 1];
            rt = t[(size_t)b * HW + irow * Ww + icol];
        }
    }

    __shared__ unsigned lds_h2[H2TOT];            // staged region (single buffer)
    __shared__ unsigned char lds_mid[10 * MIDS];  // s_{2r+1}, 10x66 used
    __shared__ int sskip;
    __shared__ int schg[4];
    __shared__ int sred[4];

    int pchg = 1;                          // changed_{r-1}, block-uniform

    // ---- 10 rounds x 2 iterations (identical to R14) ----
    for (int r = 0; r < ROUNDS; ++r) {
        const bool fin = (r == ROUNDS - 1);
        const unsigned char* cur = (r & 1) ? st1 : st0;
        unsigned char* nxt = (r & 1) ? st0 : st1;

        // poll: all neighbors part >= r+1; capture their changed_{r-1}
        if (tid < 64) {
            int nchg = 0;
            for (;;) {
                bool ok = true;
                if (nactive) {
                    int f = ld_agent_i32(nflag);
                    int part = f >> 2;
                    ok = (part >= r + 1);
                    if (ok) nchg = (part == r + 1) ? ((f >> 1) & 1) : (f & 1);
                }
                if (__all(ok)) break;
                __builtin_amdgcn_s_sleep(1);
            }
            bool unch = nactive ? (nchg == 0) : true;
            int au = __all(unch);
            if (tid == 0) sskip = au;
        }
        __syncthreads();
        const bool skip = (r > 0) && (sskip != 0) && (pchg == 0);

        const unsigned char* h2b = (const unsigned char*)lds_h2;
        unsigned n2[2];
        int chg;

        if (skip) {
            n2[0] = h2b[(tr + 2) * 80 + tc + 8];
            n2[1] = h2b[(tr + 2) * 80 + tc + 9];
            chg = 0;
            if (!fin && tid == 0)
                st_agent_i32(&flags[bid << 4], ((r + 2) << 2) | (0 << 1) | pchg);
        } else {
            if (tid < H2TOT) {
                const unsigned char* base2 =
                    cur + (size_t)b * HW + (row0 - 2) * Ww + (col0 - 8);
                const int hr = tid / H2DW, hc = tid - hr * H2DW;
                lds_h2[tid] = ld_agent_u32(base2 + hr * Ww + hc * 4);
            }
            __syncthreads();

#pragma unroll
            for (int j = 0; j < 2; ++j) {
                unsigned m = mf_state<80>(h2b + (tr + 1) * 80 + tc + 7 + j,
                                          wall[j], tj[j], Lg45, Lg55);
                lds_mid[(tr + 1) * MIDS + tc + j + 1] = (unsigned char)m;
            }
            if (ringv) {
                unsigned m = mf_state<80>(h2b + rer * 80 + rec + 6,
                                          rw, rt, Lg45, Lg55);
                lds_mid[rer * MIDS + rec] = (unsigned char)m;
            }
            __syncthreads();

#pragma unroll
            for (int j = 0; j < 2; ++j)
                n2[j] = mf_state<MIDS>(lds_mid + tr * MIDS + tc + j,
                                       wall[j], tj[j], Lg45, Lg55);

            bool diff = (n2[0] != (unsigned)h2b[(tr + 2) * 80 + tc + 8]) ||
                        (n2[1] != (unsigned)h2b[(tr + 2) * 80 + tc + 9]);
            {
                int any = __any(diff);
                if ((tid & 63) == 0) schg[tid >> 6] = any;
            }
            if (!fin)
                st_agent_u16(nxt + gp, (unsigned short)(n2[0] | (n2[1] << 8)));
            __syncthreads();              // drains state stores + schg writes
            chg = (schg[0] | schg[1] | schg[2] | schg[3]) ? 1 : 0;
            if (!fin && tid == 0)
                st_agent_i32(&flags[bid << 4], ((r + 2) << 2) | (chg << 1) | pchg);
        }
        pchg = chg;

        if (fin) {
            const float o0 = (n2[0] & 2) ? 1.0f : 0.0f;
            const float o1 = (n2[1] & 2) ? 1.0f : 0.0f;
            reinterpret_cast<float2*>(out)[gp >> 1] = make_float2(o0, o1);
            int cnt = (o0 != 0.0f) + (o1 != 0.0f);
            const int lane = tid & 63;
            const int wv = tid >> 6;
#pragma unroll
            for (int off = 32; off; off >>= 1) cnt += __shfl_down(cnt, off, 64);
            if (lane == 0) sred[wv] = cnt;
            __syncthreads();
            if (tid == 0) {
                int tot = sred[0] + sred[1] + sred[2] + sred[3];
                st_agent_i32(&partial[bid], tot);
            }
        }
    }

    // ---- final global sync (partials), then block 0 reduces -> valid ----
    __syncthreads();                      // drain partial store
    if (tid == 0)
        __hip_atomic_fetch_add(&arrive[(bid & 15) << 4], 1,
                               __ATOMIC_RELAXED, __HIP_MEMORY_SCOPE_AGENT);
    if (bid == 0) {
        if (tid < 64) {
            for (;;) {
                int v = 0;
                if (tid < 16) v = ld_agent_i32(&arrive[tid << 4]);
#pragma unroll
                for (int off = 1; off < 64; off <<= 1) v += __shfl_xor(v, off, 64);
                if (v >= NBLK) break;
                __builtin_amdgcn_s_sleep(1);
            }
        }
        __syncthreads();
        const int wv = tid >> 6;          // batch 0..3
        const int lane = tid & 63;
        const int base = wv * BLKS_PER_B; // 288 partials per batch = 4x64 + 32
        int s = 0;
#pragma unroll
        for (int k = 0; k < 4; ++k) s += ld_agent_i32(&partial[base + 64 * k + lane]);
        if (lane < 32) s += ld_agent_i32(&partial[base + 256 + lane]);
#pragma unroll
        for (int off = 32; off; off >>= 1) s += __shfl_down(s, off, 64);
        if (lane == 0) {
            float cf = (float)s;
            const float lo = (float)(147456.0 * 0.05);
            const float hi = (float)(147456.0 * 0.95);
            out[NPIX + wv] = (cf >= lo && cf <= hi) ? 1.0f : 0.0f;
        }
    }
}

}  // namespace

extern "C" void kernel_launch(void* const* d_in, const int* in_sizes, int n_in,
                              void* d_out, int out_size, void* d_ws, size_t ws_size,
                              hipStream_t stream) {
    const float* x  = (const float*)d_in[0];
    const float* tg = (const float*)d_in[1];
    const float* fm = (const float*)d_in[2];
    float* out = (float*)d_out;

    char* ws = (char*)d_ws;
    // layout (bytes):
    //   arrive : 0      .. 1024      (16 x 64B)
    //   flags  : 1024   .. 74752     (1152 x 64B)
    //   partial: 74752  .. 79360
    //   pad    : 79360  .. 81920     (overhang-safe)
    //   st0    : 81920  .. +NPIX
    //   pad    : 2048
    //   st1    : .. +NPIX
    int* arrive  = (int*)ws;
    int* flags   = (int*)(ws + 1024);
    int* partial = (int*)(ws + 74752);
    unsigned char* st0 = (unsigned char*)(ws + 81920);
    unsigned char* st1 = st0 + NPIX + 2048;

    // zero arrive + flags every call (graph-captured)
    (void)hipMemsetAsync(ws, 0, 74752, stream);

    fused_kernel<<<NBLK, TPB, 0, stream>>>(x, tg, fm, out, arrive, flags,
                                           partial, st0, st1);
}